// Round 4
// baseline (150.903 us; speedup 1.0000x reference)
//
#include <hip/hip_runtime.h>

#define FFT_N 1024
#define GRID_ROWS 4096     // 4 rows (one per wave) per 256-thread block

__device__ __forceinline__ int br6(int x) { return (int)(__brev((unsigned)x) >> 26); }

__device__ __forceinline__ unsigned int f2key(float f) {
    unsigned int u = __float_as_uint(f);
    return (u & 0x80000000u) ? ~u : (u | 0x80000000u);
}
__device__ __forceinline__ float key2f(unsigned int k) {
    unsigned int u = (k & 0x80000000u) ? (k & 0x7FFFFFFFu) : ~k;
    return __uint_as_float(u);
}

__global__ void init_mm(unsigned int* mm) {
    mm[0] = 0xFFFFFFFFu;   // min key
    mm[1] = 0u;            // max key
}

// Computes the 16 final (scaled, ifftshift-signed) real outputs of row `row`
// held by `lane`: vals[k2] = y[row][ br6(lane) + 64*k2 ].  Identical code is
// inlined into both passes -> identical rounding.
__device__ __forceinline__ void fft_row_vals(const float* __restrict__ x,
                                             int row, int lane, float* vals) {
    const int b = row >> 10;
    const int p = row & 1023;
    const float* re = x + (((size_t)(b * 2) * 1024) + p) * 1024;
    const float* im = re + (size_t)1024 * 1024;

    // load: lane holds c[16*lane + r], r=0..15 (8x dwordx4, coalesced)
    float ar[16], ai[16];
    #pragma unroll
    for (int q = 0; q < 4; ++q) {
        float4 v = *reinterpret_cast<const float4*>(re + 16 * lane + 4 * q);
        ar[4 * q] = v.x; ar[4 * q + 1] = v.y; ar[4 * q + 2] = v.z; ar[4 * q + 3] = v.w;
    }
    #pragma unroll
    for (int q = 0; q < 4; ++q) {
        float4 w = *reinterpret_cast<const float4*>(im + 16 * lane + 4 * q);
        ai[4 * q] = w.x; ai[4 * q + 1] = w.y; ai[4 * q + 2] = w.z; ai[4 * q + 3] = w.w;
    }

    // 64-pt inverse DFT across lanes, radix-2 DIF (natural in, bit-rev out)
    #pragma unroll
    for (int st = 0; st < 6; ++st) {
        const int h  = 32 >> st;
        const bool hi = (lane & h) != 0;
        const float s = hi ? -1.0f : 1.0f;
        if (h > 1) {
            const int j = lane & (h - 1);
            float ang = hi ? (3.14159265358979323846f / (float)h) * (float)j : 0.0f;
            float ws, wc;
            __sincosf(ang, &ws, &wc);
            #pragma unroll
            for (int r = 0; r < 16; ++r) {
                float pr = __shfl_xor(ar[r], h);
                float pi = __shfl_xor(ai[r], h);
                float tr = fmaf(s, ar[r], pr);
                float ti = fmaf(s, ai[r], pi);
                ar[r] = tr * wc - ti * ws;
                ai[r] = tr * ws + ti * wc;
            }
        } else {
            #pragma unroll
            for (int r = 0; r < 16; ++r) {
                float pr = __shfl_xor(ar[r], 1);
                float pi = __shfl_xor(ai[r], 1);
                ar[r] = fmaf(s, ar[r], pr);
                ai[r] = fmaf(s, ai[r], pi);
            }
        }
    }

    // per-lane twiddle: e^{+i*2*pi*r*k1/1024}, k1 = br6(lane)
    const int k1 = br6(lane);
    const float theta = 6.283185307179586f * (float)k1 * (1.0f / 1024.0f);
    #pragma unroll
    for (int r = 1; r < 16; ++r) {
        float sn, cs;
        __sincosf(theta * (float)r, &sn, &cs);
        float vr = ar[r], vi = ai[r];
        ar[r] = vr * cs - vi * sn;
        ai[r] = vr * sn + vi * cs;
    }

    // in-register 16-pt inverse DFT over r; real parts only at the end
    float yr[16], yi[16];
    #pragma unroll
    for (int a = 0; a < 4; ++a) {
        float t0r = ar[a] + ar[a + 8],      t0i = ai[a] + ai[a + 8];
        float t1r = ar[a] - ar[a + 8],      t1i = ai[a] - ai[a + 8];
        float t2r = ar[a + 4] + ar[a + 12], t2i = ai[a + 4] + ai[a + 12];
        float t3r = ar[a + 4] - ar[a + 12], t3i = ai[a + 4] - ai[a + 12];
        yr[a]      = t0r + t2r;  yi[a]      = t0i + t2i;
        yr[a + 4]  = t1r - t3i;  yi[a + 4]  = t1i + t3r;
        yr[a + 8]  = t0r - t2r;  yi[a + 8]  = t0i - t2i;
        yr[a + 12] = t1r + t3i;  yi[a + 12] = t1i - t3r;
    }
    constexpr float W16R_[10] = { 1.0f, 0.92387953251f, 0.70710678119f, 0.38268343236f,
                                  0.0f, 0.0f, -0.70710678119f, 0.0f, 0.0f, -0.92387953251f };
    constexpr float W16I_[10] = { 0.0f, 0.38268343236f, 0.70710678119f, 0.92387953251f,
                                  1.0f, 0.0f, 0.70710678119f, 0.0f, 0.0f, -0.38268343236f };
    const float scale = (lane & 32) ? -9.765625e-4f : 9.765625e-4f; // (-1)^{k1}/1024
    #pragma unroll
    for (int c = 0; c < 4; ++c) {
        float zr0 = yr[4 * c];
        float zr1, zi1, zr2, zr3, zi3;
        { float wr = W16R_[c],     wi = W16I_[c];
          float vr = yr[1 + 4 * c], vi = yi[1 + 4 * c];
          zr1 = vr * wr - vi * wi; zi1 = vr * wi + vi * wr; }
        { float wr = W16R_[2 * c], wi = W16I_[2 * c];
          float vr = yr[2 + 4 * c], vi = yi[2 + 4 * c];
          zr2 = vr * wr - vi * wi; }
        { float wr = W16R_[3 * c], wi = W16I_[3 * c];
          float vr = yr[3 + 4 * c], vi = yi[3 + 4 * c];
          zr3 = vr * wr - vi * wi; zi3 = vr * wi + vi * wr; }
        float u0r = zr0 + zr2, u1r = zr0 - zr2;
        float u2r = zr1 + zr3;
        float u3i = zi1 - zi3;
        vals[c]      = (u0r + u2r) * scale;
        vals[c + 4]  = (u1r - u3i) * scale;
        vals[c + 8]  = (u0r - u2r) * scale;
        vals[c + 12] = (u1r + u3i) * scale;
    }
}

// ---- pass 1: FFT -> global min/max only (no output write) ----
__global__ __launch_bounds__(256) void minmax_pass(const float* __restrict__ x,
                                                   unsigned int* __restrict__ mm) {
    const int t    = threadIdx.x;
    const int lane = t & 63;
    const int wid  = t >> 6;
    const int row  = blockIdx.x * 4 + wid;

    float vals[16];
    fft_row_vals(x, row, lane, vals);

    float vmin = INFINITY, vmax = -INFINITY;
    #pragma unroll
    for (int k2 = 0; k2 < 16; ++k2) {
        vmin = fminf(vmin, vals[k2]);
        vmax = fmaxf(vmax, vals[k2]);
    }
    #pragma unroll
    for (int off = 32; off >= 1; off >>= 1) {
        vmin = fminf(vmin, __shfl_xor(vmin, off));
        vmax = fmaxf(vmax, __shfl_xor(vmax, off));
    }
    __shared__ float smn[4], smx[4];
    if ((t & 63) == 0) { smn[wid] = vmin; smx[wid] = vmax; }
    __syncthreads();
    if (t == 0) {
        float mn = fminf(fminf(smn[0], smn[1]), fminf(smn[2], smn[3]));
        float mx = fmaxf(fmaxf(smx[0], smx[1]), fmaxf(smx[2], smx[3]));
        atomicMin(&mm[0], f2key(mn));
        atomicMax(&mm[1], f2key(mx));
    }
}

// ---- pass 2: FFT again (input is L3-hot), normalize in-register, write once ----
__global__ __launch_bounds__(256) void write_pass(const float* __restrict__ x,
                                                  float* __restrict__ out,
                                                  const unsigned int* __restrict__ mm) {
    const int t    = threadIdx.x;
    const int lane = t & 63;
    const int wid  = t >> 6;
    const int row  = blockIdx.x * 4 + wid;

    const float mn  = key2f(mm[0]);
    const float inv = 1.0f / (key2f(mm[1]) - mn);

    float vals[16];
    fft_row_vals(x, row, lane, vals);

    const int k1 = br6(lane);
    float* orow = out + (size_t)row * FFT_N;
    #pragma unroll
    for (int k2 = 0; k2 < 16; ++k2) {
        __builtin_nontemporal_store((vals[k2] - mn) * inv, orow + k1 + (k2 << 6));
    }
}

extern "C" void kernel_launch(void* const* d_in, const int* in_sizes, int n_in,
                              void* d_out, int out_size, void* d_ws, size_t ws_size,
                              hipStream_t stream) {
    const float* x = (const float*)d_in[0];
    float* out = (float*)d_out;
    unsigned int* mm = (unsigned int*)d_ws;

    hipLaunchKernelGGL(init_mm, dim3(1), dim3(1), 0, stream, mm);
    hipLaunchKernelGGL(minmax_pass, dim3(GRID_ROWS), dim3(256), 0, stream, x, mm);
    hipLaunchKernelGGL(write_pass, dim3(GRID_ROWS), dim3(256), 0, stream, x, out, mm);
}

// Round 5
// 145.522 us; speedup vs baseline: 1.0370x; 1.0370x over previous
//
#include <hip/hip_runtime.h>
#include <hip/hip_cooperative_groups.h>

namespace cg = cooperative_groups;

#define FFT_N 1024
#define NPART 4096          // fallback ifft grid (4 rows per 256-thread block)
#define COOP_BLOCKS 1024    // 4 blocks/CU x 256 CUs; 16 rows per block

__device__ __forceinline__ int br6(int x) { return (int)(__brev((unsigned)x) >> 26); }

__device__ __forceinline__ unsigned int f2key(float f) {
    unsigned int u = __float_as_uint(f);
    return (u & 0x80000000u) ? ~u : (u | 0x80000000u);
}
__device__ __forceinline__ float key2f(unsigned int k) {
    unsigned int u = (k & 0x80000000u) ? (k & 0x7FFFFFFFu) : ~k;
    return __uint_as_float(u);
}

__global__ void init_mm(unsigned int* mm) {
    mm[0] = 0xFFFFFFFFu;
    mm[1] = 0u;
}

// 16 final (scaled, ifftshift-signed) real outputs of row `row` held by `lane`:
// vals[k2] = y[row][ br6(lane) + 64*k2 ].  Shared by all paths -> identical rounding.
__device__ __forceinline__ void fft_row_vals(const float* __restrict__ x,
                                             int row, int lane, float* vals) {
    const int b = row >> 10;
    const int p = row & 1023;
    const float* re = x + (((size_t)(b * 2) * 1024) + p) * 1024;
    const float* im = re + (size_t)1024 * 1024;

    float ar[16], ai[16];
    #pragma unroll
    for (int q = 0; q < 4; ++q) {
        float4 v = *reinterpret_cast<const float4*>(re + 16 * lane + 4 * q);
        ar[4 * q] = v.x; ar[4 * q + 1] = v.y; ar[4 * q + 2] = v.z; ar[4 * q + 3] = v.w;
    }
    #pragma unroll
    for (int q = 0; q < 4; ++q) {
        float4 w = *reinterpret_cast<const float4*>(im + 16 * lane + 4 * q);
        ai[4 * q] = w.x; ai[4 * q + 1] = w.y; ai[4 * q + 2] = w.z; ai[4 * q + 3] = w.w;
    }

    // 64-pt inverse DFT across lanes, radix-2 DIF (natural in, bit-rev out)
    #pragma unroll
    for (int st = 0; st < 6; ++st) {
        const int h  = 32 >> st;
        const bool hi = (lane & h) != 0;
        const float s = hi ? -1.0f : 1.0f;
        if (h > 1) {
            const int j = lane & (h - 1);
            float ang = hi ? (3.14159265358979323846f / (float)h) * (float)j : 0.0f;
            float ws, wc;
            __sincosf(ang, &ws, &wc);
            #pragma unroll
            for (int r = 0; r < 16; ++r) {
                float pr = __shfl_xor(ar[r], h);
                float pi = __shfl_xor(ai[r], h);
                float tr = fmaf(s, ar[r], pr);
                float ti = fmaf(s, ai[r], pi);
                ar[r] = tr * wc - ti * ws;
                ai[r] = tr * ws + ti * wc;
            }
        } else {
            #pragma unroll
            for (int r = 0; r < 16; ++r) {
                float pr = __shfl_xor(ar[r], 1);
                float pi = __shfl_xor(ai[r], 1);
                ar[r] = fmaf(s, ar[r], pr);
                ai[r] = fmaf(s, ai[r], pi);
            }
        }
    }

    // per-lane twiddle: e^{+i*2*pi*r*k1/1024}, k1 = br6(lane)
    const int k1 = br6(lane);
    const float theta = 6.283185307179586f * (float)k1 * (1.0f / 1024.0f);
    #pragma unroll
    for (int r = 1; r < 16; ++r) {
        float sn, cs;
        __sincosf(theta * (float)r, &sn, &cs);
        float vr = ar[r], vi = ai[r];
        ar[r] = vr * cs - vi * sn;
        ai[r] = vr * sn + vi * cs;
    }

    // in-register 16-pt inverse DFT over r; real parts only at the end
    float yr[16], yi[16];
    #pragma unroll
    for (int a = 0; a < 4; ++a) {
        float t0r = ar[a] + ar[a + 8],      t0i = ai[a] + ai[a + 8];
        float t1r = ar[a] - ar[a + 8],      t1i = ai[a] - ai[a + 8];
        float t2r = ar[a + 4] + ar[a + 12], t2i = ai[a + 4] + ai[a + 12];
        float t3r = ar[a + 4] - ar[a + 12], t3i = ai[a + 4] - ai[a + 12];
        yr[a]      = t0r + t2r;  yi[a]      = t0i + t2i;
        yr[a + 4]  = t1r - t3i;  yi[a + 4]  = t1i + t3r;
        yr[a + 8]  = t0r - t2r;  yi[a + 8]  = t0i - t2i;
        yr[a + 12] = t1r + t3i;  yi[a + 12] = t1i - t3r;
    }
    constexpr float W16R_[10] = { 1.0f, 0.92387953251f, 0.70710678119f, 0.38268343236f,
                                  0.0f, 0.0f, -0.70710678119f, 0.0f, 0.0f, -0.92387953251f };
    constexpr float W16I_[10] = { 0.0f, 0.38268343236f, 0.70710678119f, 0.92387953251f,
                                  1.0f, 0.0f, 0.70710678119f, 0.0f, 0.0f, -0.38268343236f };
    const float scale = (lane & 32) ? -9.765625e-4f : 9.765625e-4f; // (-1)^{k1}/1024
    #pragma unroll
    for (int c = 0; c < 4; ++c) {
        float zr0 = yr[4 * c];
        float zr1, zi1, zr2, zr3, zi3;
        { float wr = W16R_[c],     wi = W16I_[c];
          float vr = yr[1 + 4 * c], vi = yi[1 + 4 * c];
          zr1 = vr * wr - vi * wi; zi1 = vr * wi + vi * wr; }
        { float wr = W16R_[2 * c], wi = W16I_[2 * c];
          float vr = yr[2 + 4 * c], vi = yi[2 + 4 * c];
          zr2 = vr * wr - vi * wi; }
        { float wr = W16R_[3 * c], wi = W16I_[3 * c];
          float vr = yr[3 + 4 * c], vi = yi[3 + 4 * c];
          zr3 = vr * wr - vi * wi; zi3 = vr * wi + vi * wr; }
        float u0r = zr0 + zr2, u1r = zr0 - zr2;
        float u2r = zr1 + zr3;
        float u3i = zi1 - zi3;
        vals[c]      = (u0r + u2r) * scale;
        vals[c + 4]  = (u1r - u3i) * scale;
        vals[c + 8]  = (u0r - u2r) * scale;
        vals[c + 12] = (u1r + u3i) * scale;
    }
}

// ================= cooperative single-pass kernel =================
// 16 rows/block: each wave does 4 rows (2 -> LDS, 2 -> regs), block min/max
// partial -> grid.sync -> all blocks reduce partials -> normalize + store once.
__global__ __launch_bounds__(256, 4) void fused_pass(const float* __restrict__ x,
                                                     float* __restrict__ out,
                                                     float* __restrict__ partials) {
    cg::grid_group grid = cg::this_grid();
    const int t    = threadIdx.x;
    const int lane = t & 63;
    const int w    = t >> 6;
    const int bid  = blockIdx.x;
    const int base_row = bid * 16 + w * 4;

    __shared__ float lds[4][2][FFT_N];   // [wave][j][k2*64+lane]  (32 KiB)
    __shared__ float smn[4], smx[4], bmm[2];

    float vmin = INFINITY, vmax = -INFINITY;
    float keep2[16], keep3[16];

    {
        float vals[16];
        fft_row_vals(x, base_row + 0, lane, vals);
        #pragma unroll
        for (int k2 = 0; k2 < 16; ++k2) {
            lds[w][0][k2 * 64 + lane] = vals[k2];
            vmin = fminf(vmin, vals[k2]); vmax = fmaxf(vmax, vals[k2]);
        }
    }
    {
        float vals[16];
        fft_row_vals(x, base_row + 1, lane, vals);
        #pragma unroll
        for (int k2 = 0; k2 < 16; ++k2) {
            lds[w][1][k2 * 64 + lane] = vals[k2];
            vmin = fminf(vmin, vals[k2]); vmax = fmaxf(vmax, vals[k2]);
        }
    }
    fft_row_vals(x, base_row + 2, lane, keep2);
    #pragma unroll
    for (int k2 = 0; k2 < 16; ++k2) {
        vmin = fminf(vmin, keep2[k2]); vmax = fmaxf(vmax, keep2[k2]);
    }
    fft_row_vals(x, base_row + 3, lane, keep3);
    #pragma unroll
    for (int k2 = 0; k2 < 16; ++k2) {
        vmin = fminf(vmin, keep3[k2]); vmax = fmaxf(vmax, keep3[k2]);
    }

    #pragma unroll
    for (int off = 32; off >= 1; off >>= 1) {
        vmin = fminf(vmin, __shfl_xor(vmin, off));
        vmax = fmaxf(vmax, __shfl_xor(vmax, off));
    }
    if ((t & 63) == 0) { smn[w] = vmin; smx[w] = vmax; }
    __syncthreads();
    if (t == 0) {
        float mn = fminf(fminf(smn[0], smn[1]), fminf(smn[2], smn[3]));
        float mx = fmaxf(fmaxf(smx[0], smx[1]), fmaxf(smx[2], smx[3]));
        reinterpret_cast<float2*>(partials)[bid] = make_float2(mn, mx);
    }

    grid.sync();

    // every block reduces all 1024 partials (8 KB, cache-hot)
    float mn = INFINITY, mx = -INFINITY;
    #pragma unroll
    for (int it = 0; it < COOP_BLOCKS / 256; ++it) {
        float2 v = reinterpret_cast<const float2*>(partials)[t + it * 256];
        mn = fminf(mn, v.x); mx = fmaxf(mx, v.y);
    }
    #pragma unroll
    for (int off = 32; off >= 1; off >>= 1) {
        mn = fminf(mn, __shfl_xor(mn, off));
        mx = fmaxf(mx, __shfl_xor(mx, off));
    }
    if ((t & 63) == 0) { smn[w] = mn; smx[w] = mx; }
    __syncthreads();
    if (t == 0) {
        bmm[0] = fminf(fminf(smn[0], smn[1]), fminf(smn[2], smn[3]));
        bmm[1] = fmaxf(fmaxf(smx[0], smx[1]), fmaxf(smx[2], smx[3]));
    }
    __syncthreads();

    const float MN  = bmm[0];
    const float INV = 1.0f / (bmm[1] - MN);
    const int k1 = br6(lane);

    {
        float* orow = out + (size_t)(base_row + 2) * FFT_N;
        #pragma unroll
        for (int k2 = 0; k2 < 16; ++k2)
            __builtin_nontemporal_store((keep2[k2] - MN) * INV, orow + k1 + (k2 << 6));
    }
    {
        float* orow = out + (size_t)(base_row + 3) * FFT_N;
        #pragma unroll
        for (int k2 = 0; k2 < 16; ++k2)
            __builtin_nontemporal_store((keep3[k2] - MN) * INV, orow + k1 + (k2 << 6));
    }
    #pragma unroll
    for (int j = 0; j < 2; ++j) {
        float* orow = out + (size_t)(base_row + j) * FFT_N;
        #pragma unroll
        for (int k2 = 0; k2 < 16; ++k2) {
            float v = lds[w][j][k2 * 64 + lane];
            __builtin_nontemporal_store((v - MN) * INV, orow + k1 + (k2 << 6));
        }
    }
}

// ================= fallback (proven round-3 path) =================
template <bool USE_ATOMIC>
__global__ __launch_bounds__(256) void ifft_rows(const float* __restrict__ x,
                                                 float* __restrict__ out,
                                                 float* __restrict__ partials,
                                                 unsigned int* __restrict__ mm) {
    const int t    = threadIdx.x;
    const int lane = t & 63;
    const int wid  = t >> 6;
    const int row  = blockIdx.x * 4 + wid;

    float vals[16];
    fft_row_vals(x, row, lane, vals);

    float vmin = INFINITY, vmax = -INFINITY;
    #pragma unroll
    for (int k2 = 0; k2 < 16; ++k2) {
        vmin = fminf(vmin, vals[k2]);
        vmax = fmaxf(vmax, vals[k2]);
    }
    const int k1 = br6(lane);
    float* orow = out + (size_t)row * FFT_N;
    #pragma unroll
    for (int k2 = 0; k2 < 16; ++k2) orow[k1 + (k2 << 6)] = vals[k2];

    #pragma unroll
    for (int off = 32; off >= 1; off >>= 1) {
        vmin = fminf(vmin, __shfl_xor(vmin, off));
        vmax = fmaxf(vmax, __shfl_xor(vmax, off));
    }
    __shared__ float smn[4], smx[4];
    if ((t & 63) == 0) { smn[wid] = vmin; smx[wid] = vmax; }
    __syncthreads();
    if (t == 0) {
        float mn = fminf(fminf(smn[0], smn[1]), fminf(smn[2], smn[3]));
        float mx = fmaxf(fmaxf(smx[0], smx[1]), fmaxf(smx[2], smx[3]));
        if (USE_ATOMIC) {
            atomicMin(&mm[0], f2key(mn));
            atomicMax(&mm[1], f2key(mx));
        } else {
            partials[2 * blockIdx.x]     = mn;
            partials[2 * blockIdx.x + 1] = mx;
        }
    }
}

__global__ __launch_bounds__(256) void reduce_mm(const float* __restrict__ partials,
                                                 float* __restrict__ mm) {
    float mn = INFINITY, mx = -INFINITY;
    for (int i = threadIdx.x; i < NPART; i += 256) {
        float2 v = reinterpret_cast<const float2*>(partials)[i];
        mn = fminf(mn, v.x);
        mx = fmaxf(mx, v.y);
    }
    #pragma unroll
    for (int off = 32; off >= 1; off >>= 1) {
        mn = fminf(mn, __shfl_xor(mn, off));
        mx = fmaxf(mx, __shfl_xor(mx, off));
    }
    __shared__ float smn[4], smx[4];
    const int wid = threadIdx.x >> 6;
    if ((threadIdx.x & 63) == 0) { smn[wid] = mn; smx[wid] = mx; }
    __syncthreads();
    if (threadIdx.x == 0) {
        mm[0] = fminf(fminf(smn[0], smn[1]), fminf(smn[2], smn[3]));
        mm[1] = fmaxf(fmaxf(smx[0], smx[1]), fmaxf(smx[2], smx[3]));
    }
}

template <bool FROM_KEYS>
__global__ __launch_bounds__(256) void normalize_k(float* __restrict__ out,
                                                   const void* __restrict__ mmv,
                                                   int n4) {
    float mn, mx;
    if (FROM_KEYS) {
        const unsigned int* mm = (const unsigned int*)mmv;
        mn = key2f(mm[0]); mx = key2f(mm[1]);
    } else {
        const float* mm = (const float*)mmv;
        mn = mm[0]; mx = mm[1];
    }
    const float inv = 1.0f / (mx - mn);
    float4* o4 = reinterpret_cast<float4*>(out);
    for (int i = blockIdx.x * blockDim.x + threadIdx.x; i < n4;
         i += gridDim.x * blockDim.x) {
        float4 v = o4[i];
        v.x = (v.x - mn) * inv;
        v.y = (v.y - mn) * inv;
        v.z = (v.z - mn) * inv;
        v.w = (v.w - mn) * inv;
        o4[i] = v;
    }
}

extern "C" void kernel_launch(void* const* d_in, const int* in_sizes, int n_in,
                              void* d_out, int out_size, void* d_ws, size_t ws_size,
                              hipStream_t stream) {
    const float* x = (const float*)d_in[0];
    float* out = (float*)d_out;
    const int n4 = out_size / 4;

    // ---- preferred: cooperative single-pass ----
    if (ws_size >= (size_t)(2 * COOP_BLOCKS) * sizeof(float)) {
        float* partials = (float*)d_ws;
        void* args[3] = { (void*)&x, (void*)&out, (void*)&partials };
        hipError_t e = hipLaunchCooperativeKernel((const void*)fused_pass,
                                                  dim3(COOP_BLOCKS), dim3(256),
                                                  args, 0, stream);
        if (e == hipSuccess) return;
    }

    // ---- fallback: proven 3-kernel chain (bit-identical output) ----
    if (ws_size >= (size_t)(2 * NPART + 2) * sizeof(float)) {
        float* partials = (float*)d_ws;
        float* mm = partials + 2 * NPART;
        hipLaunchKernelGGL((ifft_rows<false>), dim3(NPART), dim3(256), 0, stream,
                           x, out, partials, nullptr);
        hipLaunchKernelGGL(reduce_mm, dim3(1), dim3(256), 0, stream, partials, mm);
        hipLaunchKernelGGL((normalize_k<false>), dim3(2048), dim3(256), 0, stream,
                           out, (const void*)mm, n4);
    } else {
        unsigned int* mm = (unsigned int*)d_ws;
        hipLaunchKernelGGL(init_mm, dim3(1), dim3(1), 0, stream, mm);
        hipLaunchKernelGGL((ifft_rows<true>), dim3(NPART), dim3(256), 0, stream,
                           x, out, nullptr, mm);
        hipLaunchKernelGGL((normalize_k<true>), dim3(2048), dim3(256), 0, stream,
                           out, (const void*)mm, n4);
    }
}

// Round 6
// 67.931 us; speedup vs baseline: 2.2214x; 2.1422x over previous
//
#include <hip/hip_runtime.h>

#define FFT_N 1024
#define NROWBLK 4096    // 4 rows (one per wave) per 256-thread block

__device__ __forceinline__ int br6(int x) { return (int)(__brev((unsigned)x) >> 26); }

__device__ __forceinline__ unsigned int f2key(float f) {
    unsigned int u = __float_as_uint(f);
    return (u & 0x80000000u) ? ~u : (u | 0x80000000u);
}
__device__ __forceinline__ float key2f(unsigned int k) {
    unsigned int u = (k & 0x80000000u) ? (k & 0x7FFFFFFFu) : ~k;
    return __uint_as_float(u);
}

__global__ void init_mm(unsigned int* mm) {
    mm[0] = 0xFFFFFFFFu;
    mm[1] = 0u;
}

// Real-output inverse FFT of one row via Hermitian packing:
//   y[n] = Re(IFFT_1024(ifftshift(c)))[n], computed as a 512-pt complex IFFT.
// Lane `lane` ends with vals[0..15] = y[16*br6(lane) + 0..15] * (1/2048-scaled).
__device__ __forceinline__ void zifft_row(const float* __restrict__ re,
                                          const float* __restrict__ im,
                                          int lane, float* vals) {
    // ---- load the 4 mirror operands for k = lane + 64j, j=0..7 ----
    float ur[8], ui[8], pr[8], pi[8], qr[8], qi[8], vr[8], vi[8];
    #pragma unroll
    for (int j = 0; j < 8; ++j) {
        const int k  = lane + 64 * j;
        const int iq = 512 - k;               // in [1,512]
        const int iv = (1024 - k) & 1023;     // wrap only at k=0
        ur[j] = re[k];       ui[j] = im[k];
        pr[j] = re[k + 512]; pi[j] = im[k + 512];
        qr[j] = re[iq];      qi[j] = im[iq];
        vr[j] = re[iv];      vi[j] = im[iv];
    }

    // ---- form Z'[k] = A' + i*W^k*B',  W^k = e^{+2pi i k/1024} ----
    float Zr[8], Zi[8];
    #pragma unroll
    for (int j = 0; j < 8; ++j) {
        const int k = lane + 64 * j;
        float Ar = pr[j] + ur[j] + qr[j] + vr[j];
        float Ai = pi[j] + ui[j] - qi[j] - vi[j];
        float Br = pr[j] - ur[j] + qr[j] - vr[j];
        float Bi = pi[j] - ui[j] - qi[j] + vi[j];
        float s, c;
        __sincosf(6.283185307179586e-3f * 0.9765625f * (float)k, &s, &c); // 2pi*k/1024
        Zr[j] = Ar - (c * Bi + s * Br);
        Zi[j] = Ai + (c * Br - s * Bi);
    }

    // ---- in-register 8-pt inverse DIF over j (natural in, bit-rev out) ----
    const float R = 0.70710678118654752f;
    float tr, ti;
    // layer 1: span 4, twiddle W8^t on (a-b)
    tr = Zr[0]-Zr[4]; ti = Zi[0]-Zi[4]; Zr[0]+=Zr[4]; Zi[0]+=Zi[4]; Zr[4]=tr;        Zi[4]=ti;
    tr = Zr[1]-Zr[5]; ti = Zi[1]-Zi[5]; Zr[1]+=Zr[5]; Zi[1]+=Zi[5]; Zr[5]=R*(tr-ti); Zi[5]=R*(tr+ti);
    tr = Zr[2]-Zr[6]; ti = Zi[2]-Zi[6]; Zr[2]+=Zr[6]; Zi[2]+=Zi[6]; Zr[6]=-ti;       Zi[6]=tr;
    tr = Zr[3]-Zr[7]; ti = Zi[3]-Zi[7]; Zr[3]+=Zr[7]; Zi[3]+=Zi[7]; Zr[7]=-R*(tr+ti);Zi[7]=R*(tr-ti);
    // layer 2: span 2, twiddles {1, i}
    tr = Zr[0]-Zr[2]; ti = Zi[0]-Zi[2]; Zr[0]+=Zr[2]; Zi[0]+=Zi[2]; Zr[2]=tr;  Zi[2]=ti;
    tr = Zr[1]-Zr[3]; ti = Zi[1]-Zi[3]; Zr[1]+=Zr[3]; Zi[1]+=Zi[3]; Zr[3]=-ti; Zi[3]=tr;
    tr = Zr[4]-Zr[6]; ti = Zi[4]-Zi[6]; Zr[4]+=Zr[6]; Zi[4]+=Zi[6]; Zr[6]=tr;  Zi[6]=ti;
    tr = Zr[5]-Zr[7]; ti = Zi[5]-Zi[7]; Zr[5]+=Zr[7]; Zi[5]+=Zi[7]; Zr[7]=-ti; Zi[7]=tr;
    // layer 3: span 1
    tr = Zr[0]-Zr[1]; ti = Zi[0]-Zi[1]; Zr[0]+=Zr[1]; Zi[0]+=Zi[1]; Zr[1]=tr; Zi[1]=ti;
    tr = Zr[2]-Zr[3]; ti = Zi[2]-Zi[3]; Zr[2]+=Zr[3]; Zi[2]+=Zi[3]; Zr[3]=tr; Zi[3]=ti;
    tr = Zr[4]-Zr[5]; ti = Zi[4]-Zi[5]; Zr[4]+=Zr[5]; Zi[4]+=Zi[5]; Zr[5]=tr; Zi[5]=ti;
    tr = Zr[6]-Zr[7]; ti = Zi[6]-Zi[7]; Zr[6]+=Zr[7]; Zi[6]+=Zi[7]; Zr[7]=tr; Zi[7]=ti;
    // reg t now holds inner-DFT output m2 = br3(t)

    // ---- per-lane twiddle e^{+2pi i * lane * m2 / 512} ----
    constexpr int BR3[8] = {0, 4, 2, 6, 1, 5, 3, 7};
    #pragma unroll
    for (int t = 1; t < 8; ++t) {
        float ang = 1.2271846303085129e-2f * (float)(lane * BR3[t]); // 2pi/512 * lane*m2
        float s, c;
        __sincosf(ang, &s, &c);
        float xr = Zr[t], xi = Zi[t];
        Zr[t] = xr * c - xi * s;
        Zi[t] = xr * s + xi * c;
    }

    // ---- 64-pt inverse DFT across lanes, radix-2 DIF (natural in, bit-rev out) ----
    #pragma unroll
    for (int st = 0; st < 6; ++st) {
        const int h   = 32 >> st;
        const bool hi = (lane & h) != 0;
        const float sgn = hi ? -1.0f : 1.0f;
        if (h > 1) {
            const int j = lane & (h - 1);
            float ang = hi ? (3.14159265358979323846f / (float)h) * (float)j : 0.0f;
            float ws, wc;
            __sincosf(ang, &ws, &wc);
            #pragma unroll
            for (int r = 0; r < 8; ++r) {
                float prt = __shfl_xor(Zr[r], h);
                float pit = __shfl_xor(Zi[r], h);
                float t1 = fmaf(sgn, Zr[r], prt);
                float t2 = fmaf(sgn, Zi[r], pit);
                Zr[r] = t1 * wc - t2 * ws;
                Zi[r] = t1 * ws + t2 * wc;
            }
        } else {
            #pragma unroll
            for (int r = 0; r < 8; ++r) {
                float prt = __shfl_xor(Zr[r], 1);
                float pit = __shfl_xor(Zi[r], 1);
                Zr[r] = fmaf(sgn, Zr[r], prt);
                Zi[r] = fmaf(sgn, Zi[r], pit);
            }
        }
    }

    // ---- unpack: reg t holds w[m], m = br3(t) + 8*br6(lane);
    //      y[2m] = Re*SC, y[2m+1] = Im*SC, SC = 1/2048 ----
    const float SC = 4.8828125e-4f;
    #pragma unroll
    for (int t = 0; t < 8; ++t) {
        vals[2 * BR3[t]]     = Zr[t] * SC;
        vals[2 * BR3[t] + 1] = Zi[t] * SC;
    }
}

template <bool USE_ATOMIC>
__global__ __launch_bounds__(256, 4) void zifft_rows(const float* __restrict__ x,
                                                     float* __restrict__ out,
                                                     float* __restrict__ partials,
                                                     unsigned int* __restrict__ mm) {
    const int t    = threadIdx.x;
    const int lane = t & 63;
    const int wid  = t >> 6;
    const int row  = blockIdx.x * 4 + wid;     // 0 .. 16383
    const int b    = row >> 10;
    const int p    = row & 1023;
    const float* re = x + (((size_t)(b * 2) * 1024) + p) * 1024;
    const float* im = re + (size_t)1024 * 1024;

    float vals[16];
    zifft_row(re, im, lane, vals);

    float vmin = INFINITY, vmax = -INFINITY;
    #pragma unroll
    for (int i = 0; i < 16; ++i) {
        vmin = fminf(vmin, vals[i]);
        vmax = fmaxf(vmax, vals[i]);
    }

    // contiguous 16-float store per lane (4x float4), lane chunk = 16*br6(lane)
    float* obase = out + (size_t)row * FFT_N + 16 * br6(lane);
    #pragma unroll
    for (int q = 0; q < 4; ++q) {
        *reinterpret_cast<float4*>(obase + 4 * q) =
            make_float4(vals[4 * q], vals[4 * q + 1], vals[4 * q + 2], vals[4 * q + 3]);
    }

    #pragma unroll
    for (int off = 32; off >= 1; off >>= 1) {
        vmin = fminf(vmin, __shfl_xor(vmin, off));
        vmax = fmaxf(vmax, __shfl_xor(vmax, off));
    }
    __shared__ float smn[4], smx[4];
    if ((t & 63) == 0) { smn[wid] = vmin; smx[wid] = vmax; }
    __syncthreads();
    if (t == 0) {
        float mn = fminf(fminf(smn[0], smn[1]), fminf(smn[2], smn[3]));
        float mx = fmaxf(fmaxf(smx[0], smx[1]), fmaxf(smx[2], smx[3]));
        if (USE_ATOMIC) {
            atomicMin(&mm[0], f2key(mn));
            atomicMax(&mm[1], f2key(mx));
        } else {
            partials[2 * blockIdx.x]     = mn;
            partials[2 * blockIdx.x + 1] = mx;
        }
    }
}

__global__ __launch_bounds__(256) void reduce_mm(const float* __restrict__ partials,
                                                 float* __restrict__ mm) {
    float mn = INFINITY, mx = -INFINITY;
    for (int i = threadIdx.x; i < NROWBLK; i += 256) {
        float2 v = reinterpret_cast<const float2*>(partials)[i];
        mn = fminf(mn, v.x);
        mx = fmaxf(mx, v.y);
    }
    #pragma unroll
    for (int off = 32; off >= 1; off >>= 1) {
        mn = fminf(mn, __shfl_xor(mn, off));
        mx = fmaxf(mx, __shfl_xor(mx, off));
    }
    __shared__ float smn[4], smx[4];
    const int wid = threadIdx.x >> 6;
    if ((threadIdx.x & 63) == 0) { smn[wid] = mn; smx[wid] = mx; }
    __syncthreads();
    if (threadIdx.x == 0) {
        mm[0] = fminf(fminf(smn[0], smn[1]), fminf(smn[2], smn[3]));
        mm[1] = fmaxf(fmaxf(smx[0], smx[1]), fmaxf(smx[2], smx[3]));
    }
}

template <bool FROM_KEYS>
__global__ __launch_bounds__(256) void normalize_k(float* __restrict__ out,
                                                   const void* __restrict__ mmv,
                                                   int n4) {
    float mn, mx;
    if (FROM_KEYS) {
        const unsigned int* mm = (const unsigned int*)mmv;
        mn = key2f(mm[0]); mx = key2f(mm[1]);
    } else {
        const float* mm = (const float*)mmv;
        mn = mm[0]; mx = mm[1];
    }
    const float inv = 1.0f / (mx - mn);
    float4* o4 = reinterpret_cast<float4*>(out);
    for (int i = blockIdx.x * blockDim.x + threadIdx.x; i < n4;
         i += gridDim.x * blockDim.x) {
        float4 v = o4[i];
        v.x = (v.x - mn) * inv;
        v.y = (v.y - mn) * inv;
        v.z = (v.z - mn) * inv;
        v.w = (v.w - mn) * inv;
        o4[i] = v;
    }
}

extern "C" void kernel_launch(void* const* d_in, const int* in_sizes, int n_in,
                              void* d_out, int out_size, void* d_ws, size_t ws_size,
                              hipStream_t stream) {
    const float* x = (const float*)d_in[0];
    float* out = (float*)d_out;
    const int n4 = out_size / 4;

    if (ws_size >= (size_t)(2 * NROWBLK + 2) * sizeof(float)) {
        float* partials = (float*)d_ws;
        float* mm = partials + 2 * NROWBLK;
        hipLaunchKernelGGL((zifft_rows<false>), dim3(NROWBLK), dim3(256), 0, stream,
                           x, out, partials, nullptr);
        hipLaunchKernelGGL(reduce_mm, dim3(1), dim3(256), 0, stream, partials, mm);
        hipLaunchKernelGGL((normalize_k<false>), dim3(2048), dim3(256), 0, stream,
                           out, (const void*)mm, n4);
    } else {
        unsigned int* mm = (unsigned int*)d_ws;
        hipLaunchKernelGGL(init_mm, dim3(1), dim3(1), 0, stream, mm);
        hipLaunchKernelGGL((zifft_rows<true>), dim3(NROWBLK), dim3(256), 0, stream,
                           x, out, nullptr, mm);
        hipLaunchKernelGGL((normalize_k<true>), dim3(2048), dim3(256), 0, stream,
                           out, (const void*)mm, n4);
    }
}